// Round 5
// baseline (568.695 us; speedup 1.0000x reference)
//
#include <hip/hip_runtime.h>
#include <hip/hip_bf16.h>
#include <stdint.h>

// Problem constants: B=4, SEG=1024, MEM=1024, TOTAL=2048, D=E=128, H=8
typedef __bf16 bf16;
typedef _Float16 f16;
typedef __attribute__((ext_vector_type(8))) __bf16 bf16x8;
typedef __attribute__((ext_vector_type(4))) __bf16 bf16x4;
typedef __attribute__((ext_vector_type(8))) _Float16 f16x8;
typedef __attribute__((ext_vector_type(4))) float f32x4;

#define KSC 0.12764932952880681f  // log2(e)/sqrt(128)

__device__ __forceinline__ f32x4 MFMA(bf16x8 a, bf16x8 b, f32x4 c) {
  return __builtin_amdgcn_mfma_f32_16x16x32_bf16(a, b, c, 0, 0, 0);
}

__device__ __forceinline__ void GLL16(const void* g, void* l) {
  __builtin_amdgcn_global_load_lds(
      (const __attribute__((address_space(1))) void*)g,
      (__attribute__((address_space(3))) void*)l, 16, 0, 0);
}

__device__ __forceinline__ bf16 tobf(float f) { return (bf16)f; }

// ---------------- prep: pos (fast trig) + LDS-tiled weight transposes + bf16 converts ----------------
__global__ __launch_bounds__(256) void k_prep(
    const float* __restrict__ x, const float* __restrict__ mm,
    const float* __restrict__ wq, const float* __restrict__ wkv,
    const float* __restrict__ wr, const float* __restrict__ wmlp,
    bf16* __restrict__ posb, bf16* __restrict__ wq_bt, bf16* __restrict__ wkv_bt,
    bf16* __restrict__ wr_bt, bf16* __restrict__ wmlp_bt,
    bf16* __restrict__ xb, bf16* __restrict__ memb)
{
  __shared__ float T[32][33];
  const int b = blockIdx.x;
  const int tid = threadIdx.x;
  if (b < 1024) {  // posb[t][j], pos = enc[::-1] -> p = 2047 - t
    int id = b * 256 + tid;
    int t = id >> 7, j = id & 127;
    float p = (float)(2047 - t);
    float ang = p * exp2f(-(float)j * 0.20762050593046264f);  // 10000^(-j/64)
    float v = ((j & 1) == 0) ? __sinf(ang) : __cosf(ang);
    posb[id] = tobf(v);
    return;
  }
  if (b < 1664) {  // 32x32 LDS-tile transposes, f32 -> bf16
    int tb = b - 1024;
    const float* src; bf16* dst; int R, C, r0, c0;
    if (tb < 128)      { src = wq;   dst = wq_bt;   R = 128;  C = 1024; r0 = (tb >> 5) * 32;        c0 = (tb & 31) * 32; }
    else if (tb < 384) { int t2 = tb - 128; src = wkv;  dst = wkv_bt;  R = 128;  C = 2048; r0 = (t2 >> 6) * 32; c0 = (t2 & 63) * 32; }
    else if (tb < 512) { int t2 = tb - 384; src = wr;   dst = wr_bt;   R = 128;  C = 1024; r0 = (t2 >> 5) * 32; c0 = (t2 & 31) * 32; }
    else               { int t2 = tb - 512; src = wmlp; dst = wmlp_bt; R = 1024; C = 128;  r0 = (t2 >> 2) * 32; c0 = (t2 & 3) * 32; }
    int r = tid >> 3, c4 = (tid & 7) * 4;
    f32x4 v = *(const f32x4*)(src + (size_t)(r0 + r) * C + c0 + c4);
    T[r][c4] = v[0]; T[r][c4 + 1] = v[1]; T[r][c4 + 2] = v[2]; T[r][c4 + 3] = v[3];
    __syncthreads();
    bf16x4 o;
#pragma unroll
    for (int k = 0; k < 4; ++k) o[k] = tobf(T[c4 + k][r]);
    *(bf16x4*)(dst + (size_t)(c0 + r) * R + r0 + c4) = o;
    return;
  }
  {  // vectorized converts
    int cb = b - 1664;
    if (cb < 512) {
      int i = cb * 256 + tid;
      f32x4 v = *(const f32x4*)(x + (size_t)i * 4);
      bf16x4 o; o[0]=tobf(v[0]); o[1]=tobf(v[1]); o[2]=tobf(v[2]); o[3]=tobf(v[3]);
      *(bf16x4*)(xb + (size_t)i * 4) = o;
    } else {
      int i = (cb - 512) * 256 + tid;
      f32x4 v = *(const f32x4*)(mm + (size_t)i * 4);
      bf16x4 o; o[0]=tobf(v[0]); o[1]=tobf(v[1]); o[2]=tobf(v[2]); o[3]=tobf(v[3]);
      *(bf16x4*)(memb + (size_t)i * 4) = o;
    }
  }
}

// ---------------- projection GEMM: C[64x128 tile] = A[64x128] * W[128xN], scatter epilogue ----------------
// MODE 0: Q-proj -> out0 = (q+u1)*KSC, out1 = (q+u2)*KSC
// MODE 1: KV-proj -> out0 = k, out1 = v
// MODE 2: R-proj -> out0 = r (2112 rows: row t mirrored at 2048+t for t<64)
template <int MODE>
__global__ __launch_bounds__(256, 2) void k_proj(
    const bf16* __restrict__ asrc, const bf16* __restrict__ asrc2,
    const bf16* __restrict__ wbt, bf16* __restrict__ out0, bf16* __restrict__ out1,
    const float* __restrict__ u1, const float* __restrict__ u2)
{
  __shared__ bf16 As[64 * 128];
  __shared__ bf16 Bs[128 * 128];
  const int m0 = blockIdx.x * 64;
  const int n0 = blockIdx.y * 128;
  const int tid = threadIdx.x;
  const int w = tid >> 6, lane = tid & 63, g = lane >> 4, c = lane & 15;

#pragma unroll
  for (int it = 0; it < 4; ++it) {
    int ch = w * 256 + it * 64 + lane;
    int row = ch >> 4, cc = ch & 15;
    int scc = cc ^ (row & 7);
    const bf16* src;
    if (MODE == 1) {
      int rg = m0 + row;
      int bb = rg >> 11, t = rg & 2047;
      src = (t < 1024) ? (asrc2 + (size_t)(bb * 1024 + t) * 128)
                       : (asrc + (size_t)(bb * 1024 + (t - 1024)) * 128);
    } else {
      src = asrc + (size_t)(m0 + row) * 128;
    }
    GLL16(src + scc * 8, (char*)As + (w * 256 + it * 64) * 16);
  }
#pragma unroll
  for (int it = 0; it < 8; ++it) {
    int ch = w * 512 + it * 64 + lane;
    int n = ch >> 4, cc = ch & 15;
    int scc = cc ^ (n & 7);
    GLL16(wbt + (size_t)(n0 + n) * 128 + scc * 8, (char*)Bs + (w * 512 + it * 64) * 16);
  }
  __syncthreads();

  f32x4 acc[8] = {};
#pragma unroll
  for (int kk = 0; kk < 4; ++kk) {
    bf16x8 a = *(const bf16x8*)((const char*)As + (16 * w + c) * 256 + (((4 * kk + g) ^ (c & 7)) << 4));
#pragma unroll
    for (int fo = 0; fo < 8; ++fo) {
      bf16x8 b = *(const bf16x8*)((const char*)Bs + (16 * fo + c) * 256 + (((4 * kk + g) ^ (c & 7)) << 4));
      acc[fo] = MFMA(a, b, acc[fo]);
    }
  }

#pragma unroll
  for (int fo = 0; fo < 8; ++fo) {
#pragma unroll
    for (int j = 0; j < 4; ++j) {
      int rg = m0 + 16 * w + 4 * g + j;
      int cg = n0 + 16 * fo + c;
      float av = acc[fo][j];
      if (MODE == 0) {
        int b = rg >> 10, s2 = rg & 1023;
        int nn = s2 >> 7;
        int s = ((s2 & 127) << 3) | (cg >> 7);
        int e = cg & 127;
        size_t idx = ((size_t)((b * 8 + nn) * 1024 + s)) * 128 + e;
        out0[idx] = tobf((av + u1[nn * 128 + e]) * KSC);
        out1[idx] = tobf((av + u2[nn * 128 + e]) * KSC);
      } else if (MODE == 1) {
        int bb = rg >> 11, t = rg & 2047;
        int nn = (t >> 7) & 7;
        int hlf = (t >> 10) & 1;
        int t2 = ((t & 127) << 4) | (cg >> 7);
        int e = cg & 127;
        bf16 v = tobf(av);
        if (bb < 2)
          out0[((size_t)(((2 * bb + hlf) * 8 + nn) * 2048 + t2)) * 128 + e] = v;
        else
          out1[((size_t)(((2 * (bb - 2) + hlf) * 8 + nn) * 2048 + t2)) * 128 + e] = v;
      } else {
        int nn = rg >> 8;
        int t = ((rg & 255) << 3) | (cg >> 7);
        int e = cg & 127;
        bf16 v = tobf(av);
        out0[((size_t)(nn * 2112 + t)) * 128 + e] = v;
        if (t < 64) out0[((size_t)(nn * 2112 + 2048 + t)) * 128 + e] = v;  // wrap extension
      }
    }
  }
}

// ---------------- V transpose: vh[bh][t][e] -> vht[bh][e][t] ----------------
__global__ __launch_bounds__(256) void k_vtrans(const bf16* __restrict__ vh, bf16* __restrict__ vht)
{
  __shared__ bf16 T[64][72];
  int bt = blockIdx.x * 64, be = blockIdx.y * 64, bh = blockIdx.z;
  const bf16* src = vh + (size_t)bh * 2048 * 128;
  bf16* dst = vht + (size_t)bh * 128 * 2048;
#pragma unroll
  for (int i2 = 0; i2 < 2; ++i2) {
    int ch = i2 * 256 + threadIdx.x;
    int tt = ch >> 3, cc = ch & 7;
    bf16x8 v = *(const bf16x8*)(src + (size_t)(bt + tt) * 128 + be + cc * 8);
    *(bf16x8*)&T[tt][cc * 8] = v;
  }
  __syncthreads();
#pragma unroll
  for (int i2 = 0; i2 < 2; ++i2) {
    int ch = i2 * 256 + threadIdx.x;
    int ee = ch >> 3, c2 = ch & 7;
    bf16x8 o;
#pragma unroll
    for (int m = 0; m < 8; ++m) o[m] = T[c2 * 8 + m][ee];
    *(bf16x8*)(dst + (size_t)(be + ee) * 2048 + bt + c2 * 8) = o;
  }
}

// ---------------- flash attention (t-split halves, single-buffer K/V, 2-barrier pipeline) ----------------
// grid 1024: x = bh<<5 | qb<<1 | half. Each half-block writes partial (m, l, O-hat f16).
__global__ __launch_bounds__(256, 3) void k_flash(
    const bf16* __restrict__ qhk, const bf16* __restrict__ qhr,
    const bf16* __restrict__ kh, const bf16* __restrict__ vht,
    const bf16* __restrict__ rhe,
    f16* __restrict__ part_O, float* __restrict__ part_m, float* __restrict__ part_l)
{
  __shared__ bf16 Ks[64 * 128];      // [t][e], chunk-XOR swizzled, single buffer
  __shared__ bf16 Vs[64 * 128];      // [e][t], chunk-XOR swizzled, single buffer
  __shared__ char QRS[4][2688];      // per-wave: qr [16 x stride 82]; P aliased [16 x stride 80]

  const int x = blockIdx.x;
  const int bh = x >> 5;
  const int qb = (x >> 1) & 15;
  const int half = x & 1;
  const int pidx = x;
  const int nh = bh & 7;
  const int s0 = qb * 64;
  const int tid = threadIdx.x;
  const int w = tid >> 6, lane = tid & 63, g = lane >> 4, c = lane & 15;

  const int nt = qb + 17;            // keys needed: t <= s0+63+1024
  const int h = nt >> 1;
  const int T0 = half ? h : 0;
  const int Tend = half ? nt : h;

  const bf16* qkb  = qhk + (size_t)bh * 1024 * 128;
  const bf16* qrb  = qhr + (size_t)bh * 1024 * 128;
  const bf16* kbase = kh + (size_t)bh * 2048 * 128;
  const bf16* vbase = vht + (size_t)bh * 128 * 2048;
  const bf16* rbase = rhe + (size_t)nh * 2112 * 128;

  // ---- strength-reduced stage pointers (init at tile T0) ----
  const bf16 *kp0, *kp1, *vp0, *vp1, *vp2, *vp3;
  {
    int ch0 = w * 256 + lane;
    int ch1 = ch0 + 64;
    int r0 = ch0 >> 4, cc0 = ch0 & 15;
    int r1 = ch1 >> 4, cc1 = ch1 & 15;
    size_t koff = (size_t)T0 * 64 * 128;
    kp0 = kbase + koff + (size_t)r0 * 128 + (cc0 ^ (r0 & 7)) * 8;
    kp1 = kbase + koff + (size_t)r1 * 128 + (cc1 ^ (r1 & 7)) * 8;
    int e0 = ch0 >> 3, t0c = ch0 & 7;
    int e1 = ch1 >> 3, t1c = ch1 & 7;
    int e2 = e0 + 16, e3 = e1 + 16;
    int voff = T0 * 64;
    vp0 = vbase + (size_t)e0 * 2048 + voff + (t0c ^ (e0 & 7)) * 8;
    vp1 = vbase + (size_t)e1 * 2048 + voff + (t1c ^ (e1 & 7)) * 8;
    vp2 = vbase + (size_t)e2 * 2048 + voff + (t0c ^ (e2 & 7)) * 8;
    vp3 = vbase + (size_t)e3 * 2048 + voff + (t1c ^ (e3 & 7)) * 8;
  }
  const int dof = (w * 256 + lane) * 16;

  auto stageK = [&]() {
    char* Kd = (char*)Ks;
    GLL16(kp0, Kd + dof);
    GLL16(kp1, Kd + dof + 1024);
    GLL16(kp0 + 1024, Kd + dof + 2048);
    GLL16(kp1 + 1024, Kd + dof + 3072);
    kp0 += 8192; kp1 += 8192;
  };
  auto stageV = [&]() {
    char* Vd = (char*)Vs;
    GLL16(vp0, Vd + dof);
    GLL16(vp1, Vd + dof + 1024);
    GLL16(vp2, Vd + dof + 2048);
    GLL16(vp3, Vd + dof + 3072);
    vp0 += 64; vp1 += 64; vp2 += 64; vp3 += 64;
  };

  // ---- Q fragments (u-terms pre-folded, prescaled) ----
  bf16x8 qfK[4], qfR[4];
  {
    int srow = s0 + 16 * w + c;
#pragma unroll
    for (int kk = 0; kk < 4; ++kk) {
      qfK[kk] = *(const bf16x8*)(qkb + (size_t)srow * 128 + kk * 32 + g * 8);
      qfR[kk] = *(const bf16x8*)(qrb + (size_t)srow * 128 + kk * 32 + g * 8);
    }
  }

  // ---- R register pipeline (mod-free 2112-row rhe) ----
  bf16x8 rf[5][4];
  const bf16* rp[5];
  {
    const int L0 = 1008 - s0 - 16 * w + c + 64 * T0;
#pragma unroll
    for (int f2 = 0; f2 < 5; ++f2) {
      rp[f2] = rbase + (size_t)(L0 + 16 * f2) * 128 + g * 8;
#pragma unroll
      for (int kk = 0; kk < 4; ++kk) rf[f2][kk] = *(const bf16x8*)(rp[f2] + kk * 32);
      rp[f2] += 64 * 128;
    }
  }

  f32x4 Ot[8] = {};
  float m_r = -1e30f, l_r = 0.f;   // per-lane: row s = c of group w

  stageK();   // K(T0)

  for (int tt = T0; tt < Tend; ++tt) {
    __syncthreads();                 // barA: drains K(tt) + rf(tt) loads
    stageV();                        // V(tt) -> Vs (lands by barB)

    // ---- S^T = K Q^T : sacc[f][j] = S[s=c][t = 16f+4g+j] ----
    f32x4 sacc[4] = {};
    __builtin_amdgcn_s_setprio(1);
#pragma unroll
    for (int kk = 0; kk < 4; ++kk) {
#pragma unroll
      for (int f = 0; f < 4; ++f) {
        bf16x8 kf = *(const bf16x8*)((const char*)Ks + (16 * f + c) * 256 + (((4 * kk + g) ^ (c & 7)) << 4));
        sacc[f] = MFMA(kf, qfK[kk], sacc[f]);
      }
    }
    // ---- QR^T: bacc[f2][j] = QR[s=c][W = 16f2+4g+j] ----
    f32x4 bacc[5] = {};
#pragma unroll
    for (int f2 = 0; f2 < 5; ++f2)
#pragma unroll
      for (int kk = 0; kk < 4; ++kk)
        bacc[f2] = MFMA(rf[f2][kk], qfR[kk], bacc[f2]);
    __builtin_amdgcn_s_setprio(0);

    // ---- qr -> per-wave LDS [s=c][W], stride 82 ----
    bf16* qrw = (bf16*)QRS[w];
#pragma unroll
    for (int f2 = 0; f2 < 5; ++f2)
#pragma unroll
      for (int j = 0; j < 4; ++j)
        qrw[c * 82 + 16 * f2 + 4 * g + j] = tobf(bacc[f2][j]);

    // ---- compose scores: z = S + bias(W = tl - c + 15); mask only on global last tile ----
    const bool lastT = (tt == nt - 1);
    float zv[4][4];
#pragma unroll
    for (int f = 0; f < 4; ++f)
#pragma unroll
      for (int j = 0; j < 4; ++j) {
        int tl = 16 * f + 4 * g + j;
        float z = sacc[f][j] + (float)qrw[c * 82 + (tl - c + 15)];
        if (lastT && (tl > 16 * w + c)) z = -1e30f;
        zv[f][j] = z;
      }

    // ---- online softmax: lane owns row c; in-lane reduce + 2 shuffles; defer-max ----
    float pm = fmaxf(fmaxf(fmaxf(zv[0][0], zv[0][1]), fmaxf(zv[0][2], zv[0][3])),
                     fmaxf(fmaxf(zv[1][0], zv[1][1]), fmaxf(zv[1][2], zv[1][3])));
    float pm2 = fmaxf(fmaxf(fmaxf(zv[2][0], zv[2][1]), fmaxf(zv[2][2], zv[2][3])),
                      fmaxf(fmaxf(zv[3][0], zv[3][1]), fmaxf(zv[3][2], zv[3][3])));
    pm = fmaxf(pm, pm2);
    pm = fmaxf(pm, __shfl_xor(pm, 16));
    pm = fmaxf(pm, __shfl_xor(pm, 32));

    float alpha = 1.f;
    if (!__all(pm <= m_r + 8.0f)) {
      float mn = fmaxf(m_r, pm);
      alpha = exp2f(m_r - mn);
      m_r = mn;
      float at[4];
#pragma unroll
      for (int j = 0; j < 4; ++j) at[j] = __shfl(alpha, 20 * g + j);
#pragma unroll
      for (int fo = 0; fo < 8; ++fo)
#pragma unroll
        for (int j = 0; j < 4; ++j) Ot[fo][j] *= at[j];
    }

    float ps = 0.f;
#pragma unroll
    for (int f = 0; f < 4; ++f)
#pragma unroll
      for (int j = 0; j < 4; ++j) { float pp = exp2f(zv[f][j] - m_r); zv[f][j] = pp; ps += pp; }
    ps += __shfl_xor(ps, 16);
    ps += __shfl_xor(ps, 32);
    l_r = l_r * alpha + ps;

    // ---- P -> LDS (per-wave, granule-XOR) ----
    bf16* pw = (bf16*)QRS[w];
#pragma unroll
    for (int f = 0; f < 4; ++f)
#pragma unroll
      for (int j = 0; j < 4; ++j) {
        int t = 16 * f + 4 * g + j;
        pw[c * 80 + ((((t >> 3) ^ (c & 7)) << 3) | (t & 7))] = tobf(zv[f][j]);
      }

    __syncthreads();                 // barB: drains V(tt); all waves done reading Ks
    const bool more = (tt + 1 < Tend);
    if (more) stageK();              // K(tt+1) -> Ks (lands by next barA)
    if (more) {                      // rf(tt+1) global->reg (drained at next barA)
#pragma unroll
      for (int f2 = 0; f2 < 5; ++f2) {
#pragma unroll
        for (int kk = 0; kk < 4; ++kk) rf[f2][kk] = *(const bf16x8*)(rp[f2] + kk * 32);
        rp[f2] += 64 * 128;
      }
    }

    // ---- O += P V ----
    __builtin_amdgcn_s_setprio(1);
#pragma unroll
    for (int kk2 = 0; kk2 < 2; ++kk2) {
      bf16x8 pa = *(const bf16x8*)(pw + c * 80 + (((4 * kk2 + g) ^ (c & 7)) << 3));
#pragma unroll
      for (int fo = 0; fo < 8; ++fo) {
        int e = 16 * fo + c;
        bf16x8 vf = *(const bf16x8*)((const char*)Vs + e * 128 + (((4 * kk2 + g) ^ (c & 7)) << 4));
        Ot[fo] = MFMA(pa, vf, Ot[fo]);
      }
    }
    __builtin_amdgcn_s_setprio(0);
  }

  // ---- partial epilogue: normalized O-hat (f16) + (m, l) f32 ----
  if (g == 0) {
    part_m[pidx * 64 + 16 * w + c] = m_r;
    part_l[pidx * 64 + 16 * w + c] = l_r;
  }
  float linv[4];
#pragma unroll
  for (int j = 0; j < 4; ++j) linv[j] = 1.f / __shfl(l_r, 20 * g + j);
  f16* po = part_O + (size_t)pidx * 8192;
#pragma unroll
  for (int j = 0; j < 4; ++j) {
    int sl = 16 * w + 4 * g + j;
#pragma unroll
    for (int fo = 0; fo < 8; ++fo)
      po[sl * 128 + 16 * fo + c] = (f16)(Ot[fo][j] * linv[j]);
  }
}

// ---------------- combine partial halves -> att2 scatter ----------------
__global__ __launch_bounds__(256) void k_combine(
    const f16* __restrict__ part_O, const float* __restrict__ part_m,
    const float* __restrict__ part_l, bf16* __restrict__ att2)
{
  int ss = blockIdx.x;             // 0..511: strip (bh = ss>>4, qb = ss&15)
  int bh = ss >> 4, qb = ss & 15;
  int p1 = (bh << 5) | (qb << 1), p2 = p1 | 1;
  int r = threadIdx.x >> 2;        // 0..63
  int e0 = (threadIdx.x & 3) * 32;
  float m1 = part_m[p1 * 64 + r], m2 = part_m[p2 * 64 + r];
  float l1 = part_l[p1 * 64 + r], l2 = part_l[p2 * 64 + r];
  float m = fmaxf(m1, m2);
  float a1 = exp2f(m1 - m) * l1, a2 = exp2f(m2 - m) * l2;
  float inv = 1.f / (a1 + a2);
  a1 *= inv; a2 *= inv;
  int sg = qb * 64 + r;
  int ib = bh >> 3, nh = bh & 7;
  bf16* ob = att2 + (size_t)ib * 1024 * 1024
           + ((size_t)(nh * 128 + (sg >> 3))) * 1024 + ((sg & 7) << 7);
  const f16* o1 = part_O + ((size_t)p1 * 64 + r) * 128 + e0;
  const f16* o2 = part_O + ((size_t)p2 * 64 + r) * 128 + e0;
#pragma unroll
  for (int i = 0; i < 32; i += 8) {
    f16x8 v1 = *(const f16x8*)(o1 + i);
    f16x8 v2 = *(const f16x8*)(o2 + i);
    bf16x8 o;
#pragma unroll
    for (int k = 0; k < 8; ++k) o[k] = tobf(a1 * (float)v1[k] + a2 * (float)v2[k]);
    *(bf16x8*)(ob + e0 + i) = o;
  }
}

// ---------------- y = att2 @ w_mlp + x, then LayerNorm ----------------
__global__ __launch_bounds__(256, 2) void k_mlp(
    const bf16* __restrict__ att2, const bf16* __restrict__ wmlp_bt,
    const float* __restrict__ x, const float* __restrict__ lng, const float* __restrict__ lnb,
    float* __restrict__ out)
{
  __shared__ bf16 As[64 * 128];
  __shared__ bf16 Bs[128 * 128];
  const int m0 = blockIdx.x * 64;
  const int tid = threadIdx.x;
  const int w = tid >> 6, lane = tid & 63, g = lane >> 4, c = lane & 15;

  f32x4 acc[8] = {};
  for (int ks = 0; ks < 8; ++ks) {
    int k0 = ks * 128;
    __syncthreads();
#pragma unroll
    for (int it = 0; it < 4; ++it) {
      int ch = w * 256 + it * 64 + lane;
      int row = ch >> 4, cc = ch & 15;
      GLL16(att2 + (size_t)(m0 + row) * 1024 + k0 + ((cc ^ (row & 7)) * 8),
            (char*)As + (w * 256 + it * 64) * 16);
    }
#pragma unroll
    for (int it = 0; it < 8; ++it) {
      int ch = w * 512 + it * 64 + lane;
      int n = ch >> 4, cc = ch & 15;
      GLL16(wmlp_bt + (size_t)n * 1024 + k0 + ((cc ^ (n & 7)) * 8),
            (char*)Bs + (w * 512 + it * 64) * 16);
    }
    __syncthreads();
#pragma unroll
    for (int kk = 0; kk < 4; ++kk) {
      bf16x8 a = *(const bf16x8*)((const char*)As + (16 * w + c) * 256 + (((4 * kk + g) ^ (c & 7)) << 4));
#pragma unroll
      for (int fo = 0; fo < 8; ++fo) {
        bf16x8 b = *(const bf16x8*)((const char*)Bs + (16 * fo + c) * 256 + (((4 * kk + g) ^ (c & 7)) << 4));
        acc[fo] = MFMA(a, b, acc[fo]);
      }
    }
  }
#pragma unroll
  for (int j = 0; j < 4; ++j) {
    int rg = m0 + 16 * w + 4 * g + j;
    float y[8];
    float s1 = 0.f, s2 = 0.f;
#pragma unroll
    for (int fo = 0; fo < 8; ++fo) {
      float v = acc[fo][j] + x[(size_t)rg * 128 + 16 * fo + c];
      y[fo] = v; s1 += v; s2 += v * v;
    }
#pragma unroll
    for (int d = 1; d < 16; d <<= 1) { s1 += __shfl_xor(s1, d); s2 += __shfl_xor(s2, d); }
    float mu = s1 * 0.0078125f;
    float var = s2 * 0.0078125f - mu * mu;
    float rs = rsqrtf(var + 1e-5f);
#pragma unroll
    for (int fo = 0; fo < 8; ++fo) {
      int e = 16 * fo + c;
      out[(size_t)rg * 128 + e] = (y[fo] - mu) * rs * lng[e] + lnb[e];
    }
  }
}

extern "C" void kernel_launch(void* const* d_in, const int* in_sizes, int n_in,
                              void* d_out, int out_size, void* d_ws, size_t ws_size,
                              hipStream_t stream)
{
  const float* x    = (const float*)d_in[0];
  const float* mm   = (const float*)d_in[1];
  const float* u1   = (const float*)d_in[3];
  const float* u2   = (const float*)d_in[4];
  const float* wq   = (const float*)d_in[5];
  const float* wkv  = (const float*)d_in[6];
  const float* wr   = (const float*)d_in[7];
  const float* wmlp = (const float*)d_in[8];
  const float* lng  = (const float*)d_in[9];
  const float* lnb  = (const float*)d_in[10];
  float* out = (float*)d_out;

  char* p = (char*)d_ws;
  bf16* posb    = (bf16*)p;  p += (size_t)262144 * 2;
  bf16* wq_bt   = (bf16*)p;  p += (size_t)131072 * 2;
  bf16* wkv_bt  = (bf16*)p;  p += (size_t)262144 * 2;
  bf16* wr_bt   = (bf16*)p;  p += (size_t)131072 * 2;
  bf16* wmlp_bt = (bf16*)p;  p += (size_t)131072 * 2;
  bf16* xb      = (bf16*)p;  p += (size_t)524288 * 2;
  bf16* memb    = (bf16*)p;  p += (size_t)524288 * 2;
  bf16* qhk     = (bf16*)p;  p += (size_t)4 * 8 * 1024 * 128 * 2;
  bf16* qhr     = (bf16*)p;  p += (size_t)4 * 8 * 1024 * 128 * 2;
  bf16* kh      = (bf16*)p;  p += (size_t)4 * 8 * 2048 * 128 * 2;
  bf16* vh      = (bf16*)p;  p += (size_t)4 * 8 * 2048 * 128 * 2;
  bf16* vht     = (bf16*)p;  p += (size_t)4 * 8 * 2048 * 128 * 2;
  bf16* rhe     = (bf16*)p;  p += (size_t)8 * 2112 * 128 * 2;
  bf16* att2    = (bf16*)p;  p += (size_t)4 * 1024 * 1024 * 2;

  // partials aliased over buffers that are dead by the time k_flash runs:
  f16*   part_O = (f16*)vh;                 // 1024*64*128*2B = 16 MB == sizeof(vh)
  float* part_m = (float*)posb;             // 1024*64*4B = 256 KB
  float* part_l = (float*)posb + 65536;     // +256 KB == sizeof(posb)

  k_prep<<<dim3(2688), dim3(256), 0, stream>>>(x, mm, wq, wkv, wr, wmlp,
                                               posb, wq_bt, wkv_bt, wr_bt, wmlp_bt, xb, memb);
  k_proj<0><<<dim3(64, 8),   dim3(256), 0, stream>>>(xb,  (const bf16*)nullptr, wq_bt,  qhk, qhr, u1, u2);
  k_proj<1><<<dim3(128, 16), dim3(256), 0, stream>>>(xb,  memb,                 wkv_bt, kh,  vh,  nullptr, nullptr);
  k_proj<2><<<dim3(32, 8),   dim3(256), 0, stream>>>(posb,(const bf16*)nullptr, wr_bt,  rhe, (bf16*)nullptr, nullptr, nullptr);
  k_vtrans<<<dim3(32, 2, 32), dim3(256), 0, stream>>>(vh, vht);
  k_flash<<<dim3(1024), dim3(256), 0, stream>>>(qhk, qhr, kh, vht, rhe, part_O, part_m, part_l);
  k_combine<<<dim3(512), dim3(256), 0, stream>>>(part_O, part_m, part_l, att2);
  k_mlp<<<dim3(64), dim3(256), 0, stream>>>(att2, wmlp_bt, x, lng, lnb, out);
}

// Round 6
// 320.847 us; speedup vs baseline: 1.7725x; 1.7725x over previous
//
#include <hip/hip_runtime.h>
#include <hip/hip_bf16.h>
#include <stdint.h>

// Problem constants: B=4, SEG=1024, MEM=1024, TOTAL=2048, D=E=128, H=8
typedef __bf16 bf16;
typedef _Float16 f16;
typedef __attribute__((ext_vector_type(8))) __bf16 bf16x8;
typedef __attribute__((ext_vector_type(4))) __bf16 bf16x4;
typedef __attribute__((ext_vector_type(8))) _Float16 f16x8;
typedef __attribute__((ext_vector_type(4))) float f32x4;

#define KSC 0.12764932952880681f  // log2(e)/sqrt(128)

__device__ __forceinline__ f32x4 MFMA(bf16x8 a, bf16x8 b, f32x4 c) {
  return __builtin_amdgcn_mfma_f32_16x16x32_bf16(a, b, c, 0, 0, 0);
}

__device__ __forceinline__ void GLL16(const void* g, void* l) {
  __builtin_amdgcn_global_load_lds(
      (const __attribute__((address_space(1))) void*)g,
      (__attribute__((address_space(3))) void*)l, 16, 0, 0);
}

__device__ __forceinline__ bf16 tobf(float f) { return (bf16)f; }

// ---------------- prep: pos (fast trig) + LDS-tiled weight transposes + bf16 converts ----------------
__global__ __launch_bounds__(256) void k_prep(
    const float* __restrict__ x, const float* __restrict__ mm,
    const float* __restrict__ wq, const float* __restrict__ wkv,
    const float* __restrict__ wr, const float* __restrict__ wmlp,
    bf16* __restrict__ posb, bf16* __restrict__ wq_bt, bf16* __restrict__ wkv_bt,
    bf16* __restrict__ wr_bt, bf16* __restrict__ wmlp_bt,
    bf16* __restrict__ xb, bf16* __restrict__ memb)
{
  __shared__ float T[32][33];
  const int b = blockIdx.x;
  const int tid = threadIdx.x;
  if (b < 1024) {  // posb[t][j], pos = enc[::-1] -> p = 2047 - t
    int id = b * 256 + tid;
    int t = id >> 7, j = id & 127;
    float p = (float)(2047 - t);
    float ang = p * exp2f(-(float)j * 0.20762050593046264f);  // 10000^(-j/64)
    float v = ((j & 1) == 0) ? __sinf(ang) : __cosf(ang);
    posb[id] = tobf(v);
    return;
  }
  if (b < 1664) {  // 32x32 LDS-tile transposes, f32 -> bf16
    int tb = b - 1024;
    const float* src; bf16* dst; int R, C, r0, c0;
    if (tb < 128)      { src = wq;   dst = wq_bt;   R = 128;  C = 1024; r0 = (tb >> 5) * 32;        c0 = (tb & 31) * 32; }
    else if (tb < 384) { int t2 = tb - 128; src = wkv;  dst = wkv_bt;  R = 128;  C = 2048; r0 = (t2 >> 6) * 32; c0 = (t2 & 63) * 32; }
    else if (tb < 512) { int t2 = tb - 384; src = wr;   dst = wr_bt;   R = 128;  C = 1024; r0 = (t2 >> 5) * 32; c0 = (t2 & 31) * 32; }
    else               { int t2 = tb - 512; src = wmlp; dst = wmlp_bt; R = 1024; C = 128;  r0 = (t2 >> 2) * 32; c0 = (t2 & 3) * 32; }
    int r = tid >> 3, c4 = (tid & 7) * 4;
    f32x4 v = *(const f32x4*)(src + (size_t)(r0 + r) * C + c0 + c4);
    T[r][c4] = v[0]; T[r][c4 + 1] = v[1]; T[r][c4 + 2] = v[2]; T[r][c4 + 3] = v[3];
    __syncthreads();
    bf16x4 o;
#pragma unroll
    for (int k = 0; k < 4; ++k) o[k] = tobf(T[c4 + k][r]);
    *(bf16x4*)(dst + (size_t)(c0 + r) * R + r0 + c4) = o;
    return;
  }
  {  // vectorized converts
    int cb = b - 1664;
    if (cb < 512) {
      int i = cb * 256 + tid;
      f32x4 v = *(const f32x4*)(x + (size_t)i * 4);
      bf16x4 o; o[0]=tobf(v[0]); o[1]=tobf(v[1]); o[2]=tobf(v[2]); o[3]=tobf(v[3]);
      *(bf16x4*)(xb + (size_t)i * 4) = o;
    } else {
      int i = (cb - 512) * 256 + tid;
      f32x4 v = *(const f32x4*)(mm + (size_t)i * 4);
      bf16x4 o; o[0]=tobf(v[0]); o[1]=tobf(v[1]); o[2]=tobf(v[2]); o[3]=tobf(v[3]);
      *(bf16x4*)(memb + (size_t)i * 4) = o;
    }
  }
}

// ---------------- projection GEMM: C[64x128 tile] = A[64x128] * W[128xN], scatter epilogue ----------------
// MODE 0: Q-proj -> out0 = (q+u1)*KSC, out1 = (q+u2)*KSC
// MODE 1: KV-proj -> out0 = k, out1 = v
// MODE 2: R-proj -> out0 = r (2112 rows: row t mirrored at 2048+t for t<64)
template <int MODE>
__global__ __launch_bounds__(256, 2) void k_proj(
    const bf16* __restrict__ asrc, const bf16* __restrict__ asrc2,
    const bf16* __restrict__ wbt, bf16* __restrict__ out0, bf16* __restrict__ out1,
    const float* __restrict__ u1, const float* __restrict__ u2)
{
  __shared__ bf16 As[64 * 128];
  __shared__ bf16 Bs[128 * 128];
  const int m0 = blockIdx.x * 64;
  const int n0 = blockIdx.y * 128;
  const int tid = threadIdx.x;
  const int w = tid >> 6, lane = tid & 63, g = lane >> 4, c = lane & 15;

#pragma unroll
  for (int it = 0; it < 4; ++it) {
    int ch = w * 256 + it * 64 + lane;
    int row = ch >> 4, cc = ch & 15;
    int scc = cc ^ (row & 7);
    const bf16* src;
    if (MODE == 1) {
      int rg = m0 + row;
      int bb = rg >> 11, t = rg & 2047;
      src = (t < 1024) ? (asrc2 + (size_t)(bb * 1024 + t) * 128)
                       : (asrc + (size_t)(bb * 1024 + (t - 1024)) * 128);
    } else {
      src = asrc + (size_t)(m0 + row) * 128;
    }
    GLL16(src + scc * 8, (char*)As + (w * 256 + it * 64) * 16);
  }
#pragma unroll
  for (int it = 0; it < 8; ++it) {
    int ch = w * 512 + it * 64 + lane;
    int n = ch >> 4, cc = ch & 15;
    int scc = cc ^ (n & 7);
    GLL16(wbt + (size_t)(n0 + n) * 128 + scc * 8, (char*)Bs + (w * 512 + it * 64) * 16);
  }
  __syncthreads();

  f32x4 acc[8] = {};
#pragma unroll
  for (int kk = 0; kk < 4; ++kk) {
    bf16x8 a = *(const bf16x8*)((const char*)As + (16 * w + c) * 256 + (((4 * kk + g) ^ (c & 7)) << 4));
#pragma unroll
    for (int fo = 0; fo < 8; ++fo) {
      bf16x8 b = *(const bf16x8*)((const char*)Bs + (16 * fo + c) * 256 + (((4 * kk + g) ^ (c & 7)) << 4));
      acc[fo] = MFMA(a, b, acc[fo]);
    }
  }

#pragma unroll
  for (int fo = 0; fo < 8; ++fo) {
#pragma unroll
    for (int j = 0; j < 4; ++j) {
      int rg = m0 + 16 * w + 4 * g + j;
      int cg = n0 + 16 * fo + c;
      float av = acc[fo][j];
      if (MODE == 0) {
        int b = rg >> 10, s2 = rg & 1023;
        int nn = s2 >> 7;
        int s = ((s2 & 127) << 3) | (cg >> 7);
        int e = cg & 127;
        size_t idx = ((size_t)((b * 8 + nn) * 1024 + s)) * 128 + e;
        out0[idx] = tobf((av + u1[nn * 128 + e]) * KSC);
        out1[idx] = tobf((av + u2[nn * 128 + e]) * KSC);
      } else if (MODE == 1) {
        int bb = rg >> 11, t = rg & 2047;
        int nn = (t >> 7) & 7;
        int hlf = (t >> 10) & 1;
        int t2 = ((t & 127) << 4) | (cg >> 7);
        int e = cg & 127;
        bf16 v = tobf(av);
        if (bb < 2)
          out0[((size_t)(((2 * bb + hlf) * 8 + nn) * 2048 + t2)) * 128 + e] = v;
        else
          out1[((size_t)(((2 * (bb - 2) + hlf) * 8 + nn) * 2048 + t2)) * 128 + e] = v;
      } else {
        int nn = rg >> 8;
        int t = ((rg & 255) << 3) | (cg >> 7);
        int e = cg & 127;
        bf16 v = tobf(av);
        out0[((size_t)(nn * 2112 + t)) * 128 + e] = v;
        if (t < 64) out0[((size_t)(nn * 2112 + 2048 + t)) * 128 + e] = v;  // wrap extension
      }
    }
  }
}

// ---------------- V transpose: vh[bh][t][e] -> vht[bh][e][t] ----------------
__global__ __launch_bounds__(256) void k_vtrans(const bf16* __restrict__ vh, bf16* __restrict__ vht)
{
  __shared__ bf16 T[64][72];
  int bt = blockIdx.x * 64, be = blockIdx.y * 64, bh = blockIdx.z;
  const bf16* src = vh + (size_t)bh * 2048 * 128;
  bf16* dst = vht + (size_t)bh * 128 * 2048;
#pragma unroll
  for (int i2 = 0; i2 < 2; ++i2) {
    int ch = i2 * 256 + threadIdx.x;
    int tt = ch >> 3, cc = ch & 7;
    bf16x8 v = *(const bf16x8*)(src + (size_t)(bt + tt) * 128 + be + cc * 8);
    *(bf16x8*)&T[tt][cc * 8] = v;
  }
  __syncthreads();
#pragma unroll
  for (int i2 = 0; i2 < 2; ++i2) {
    int ch = i2 * 256 + threadIdx.x;
    int ee = ch >> 3, c2 = ch & 7;
    bf16x8 o;
#pragma unroll
    for (int m = 0; m < 8; ++m) o[m] = T[c2 * 8 + m][ee];
    *(bf16x8*)(dst + (size_t)(be + ee) * 2048 + bt + c2 * 8) = o;
  }
}

// ---------------- flash attention (t-split halves, single-buffer K/V, 2-barrier pipeline) ----------------
// grid 1024: x = bh<<5 | qb<<1 | half. Each half-block writes partial (m, l, O-hat f16).
// NOTE launch_bounds (256,2): the min-waves arg is a VGPR CAP, not an occupancy request.
// (256,3) capped VGPRs at 84 -> massive scratch spill (R5: 1.16 GB HBM traffic/dispatch).
// Occupancy target (3 blocks/CU) comes from LDS=42.5KB alone; natural VGPR ~128 fits.
__global__ __launch_bounds__(256, 2) void k_flash(
    const bf16* __restrict__ qhk, const bf16* __restrict__ qhr,
    const bf16* __restrict__ kh, const bf16* __restrict__ vht,
    const bf16* __restrict__ rhe,
    f16* __restrict__ part_O, float* __restrict__ part_m, float* __restrict__ part_l)
{
  __shared__ bf16 Ks[64 * 128];      // [t][e], chunk-XOR swizzled, single buffer
  __shared__ bf16 Vs[64 * 128];      // [e][t], chunk-XOR swizzled, single buffer
  __shared__ char QRS[4][2688];      // per-wave: qr [16 x stride 82]; P aliased [16 x stride 80]

  const int x = blockIdx.x;
  const int bh = x >> 5;
  const int qb = (x >> 1) & 15;
  const int half = x & 1;
  const int pidx = x;
  const int nh = bh & 7;
  const int s0 = qb * 64;
  const int tid = threadIdx.x;
  const int w = tid >> 6, lane = tid & 63, g = lane >> 4, c = lane & 15;

  const int nt = qb + 17;            // keys needed: t <= s0+63+1024
  const int h = nt >> 1;
  const int T0 = half ? h : 0;
  const int Tend = half ? nt : h;

  const bf16* qkb  = qhk + (size_t)bh * 1024 * 128;
  const bf16* qrb  = qhr + (size_t)bh * 1024 * 128;
  const bf16* kbase = kh + (size_t)bh * 2048 * 128;
  const bf16* vbase = vht + (size_t)bh * 128 * 2048;
  const bf16* rbase = rhe + (size_t)nh * 2112 * 128;

  // ---- strength-reduced stage pointers (init at tile T0) ----
  const bf16 *kp0, *kp1, *vp0, *vp1, *vp2, *vp3;
  {
    int ch0 = w * 256 + lane;
    int ch1 = ch0 + 64;
    int r0 = ch0 >> 4, cc0 = ch0 & 15;
    int r1 = ch1 >> 4, cc1 = ch1 & 15;
    size_t koff = (size_t)T0 * 64 * 128;
    kp0 = kbase + koff + (size_t)r0 * 128 + (cc0 ^ (r0 & 7)) * 8;
    kp1 = kbase + koff + (size_t)r1 * 128 + (cc1 ^ (r1 & 7)) * 8;
    int e0 = ch0 >> 3, t0c = ch0 & 7;
    int e1 = ch1 >> 3, t1c = ch1 & 7;
    int e2 = e0 + 16, e3 = e1 + 16;
    int voff = T0 * 64;
    vp0 = vbase + (size_t)e0 * 2048 + voff + (t0c ^ (e0 & 7)) * 8;
    vp1 = vbase + (size_t)e1 * 2048 + voff + (t1c ^ (e1 & 7)) * 8;
    vp2 = vbase + (size_t)e2 * 2048 + voff + (t0c ^ (e2 & 7)) * 8;
    vp3 = vbase + (size_t)e3 * 2048 + voff + (t1c ^ (e3 & 7)) * 8;
  }
  const int dof = (w * 256 + lane) * 16;

  auto stageK = [&]() {
    char* Kd = (char*)Ks;
    GLL16(kp0, Kd + dof);
    GLL16(kp1, Kd + dof + 1024);
    GLL16(kp0 + 1024, Kd + dof + 2048);
    GLL16(kp1 + 1024, Kd + dof + 3072);
    kp0 += 8192; kp1 += 8192;
  };
  auto stageV = [&]() {
    char* Vd = (char*)Vs;
    GLL16(vp0, Vd + dof);
    GLL16(vp1, Vd + dof + 1024);
    GLL16(vp2, Vd + dof + 2048);
    GLL16(vp3, Vd + dof + 3072);
    vp0 += 64; vp1 += 64; vp2 += 64; vp3 += 64;
  };

  // ---- Q fragments (u-terms pre-folded, prescaled) ----
  bf16x8 qfK[4], qfR[4];
  {
    int srow = s0 + 16 * w + c;
#pragma unroll
    for (int kk = 0; kk < 4; ++kk) {
      qfK[kk] = *(const bf16x8*)(qkb + (size_t)srow * 128 + kk * 32 + g * 8);
      qfR[kk] = *(const bf16x8*)(qrb + (size_t)srow * 128 + kk * 32 + g * 8);
    }
  }

  // ---- R register pipeline (mod-free 2112-row rhe) ----
  bf16x8 rf[5][4];
  const bf16* rp[5];
  {
    const int L0 = 1008 - s0 - 16 * w + c + 64 * T0;
#pragma unroll
    for (int f2 = 0; f2 < 5; ++f2) {
      rp[f2] = rbase + (size_t)(L0 + 16 * f2) * 128 + g * 8;
#pragma unroll
      for (int kk = 0; kk < 4; ++kk) rf[f2][kk] = *(const bf16x8*)(rp[f2] + kk * 32);
      rp[f2] += 64 * 128;
    }
  }

  f32x4 Ot[8] = {};
  float m_r = -1e30f, l_r = 0.f;   // per-lane: row s = c of group w

  stageK();   // K(T0)

  for (int tt = T0; tt < Tend; ++tt) {
    __syncthreads();                 // barA: drains K(tt) + rf(tt) loads
    stageV();                        // V(tt) -> Vs (lands by barB)

    // ---- S^T = K Q^T : sacc[f][j] = S[s=c][t = 16f+4g+j] ----
    f32x4 sacc[4] = {};
    __builtin_amdgcn_s_setprio(1);
#pragma unroll
    for (int kk = 0; kk < 4; ++kk) {
#pragma unroll
      for (int f = 0; f < 4; ++f) {
        bf16x8 kf = *(const bf16x8*)((const char*)Ks + (16 * f + c) * 256 + (((4 * kk + g) ^ (c & 7)) << 4));
        sacc[f] = MFMA(kf, qfK[kk], sacc[f]);
      }
    }
    // ---- QR^T: bacc[f2][j] = QR[s=c][W = 16f2+4g+j] ----
    f32x4 bacc[5] = {};
#pragma unroll
    for (int f2 = 0; f2 < 5; ++f2)
#pragma unroll
      for (int kk = 0; kk < 4; ++kk)
        bacc[f2] = MFMA(rf[f2][kk], qfR[kk], bacc[f2]);
    __builtin_amdgcn_s_setprio(0);

    // ---- qr -> per-wave LDS [s=c][W], stride 82 ----
    bf16* qrw = (bf16*)QRS[w];
#pragma unroll
    for (int f2 = 0; f2 < 5; ++f2)
#pragma unroll
      for (int j = 0; j < 4; ++j)
        qrw[c * 82 + 16 * f2 + 4 * g + j] = tobf(bacc[f2][j]);

    // ---- compose scores: z = S + bias(W = tl - c + 15); mask only on global last tile ----
    const bool lastT = (tt == nt - 1);
    float zv[4][4];
#pragma unroll
    for (int f = 0; f < 4; ++f)
#pragma unroll
      for (int j = 0; j < 4; ++j) {
        int tl = 16 * f + 4 * g + j;
        float z = sacc[f][j] + (float)qrw[c * 82 + (tl - c + 15)];
        if (lastT && (tl > 16 * w + c)) z = -1e30f;
        zv[f][j] = z;
      }

    // ---- online softmax: lane owns row c; in-lane reduce + 2 shuffles; defer-max ----
    float pm = fmaxf(fmaxf(fmaxf(zv[0][0], zv[0][1]), fmaxf(zv[0][2], zv[0][3])),
                     fmaxf(fmaxf(zv[1][0], zv[1][1]), fmaxf(zv[1][2], zv[1][3])));
    float pm2 = fmaxf(fmaxf(fmaxf(zv[2][0], zv[2][1]), fmaxf(zv[2][2], zv[2][3])),
                      fmaxf(fmaxf(zv[3][0], zv[3][1]), fmaxf(zv[3][2], zv[3][3])));
    pm = fmaxf(pm, pm2);
    pm = fmaxf(pm, __shfl_xor(pm, 16));
    pm = fmaxf(pm, __shfl_xor(pm, 32));

    float alpha = 1.f;
    if (!__all(pm <= m_r + 8.0f)) {
      float mn = fmaxf(m_r, pm);
      alpha = exp2f(m_r - mn);
      m_r = mn;
      float at[4];
#pragma unroll
      for (int j = 0; j < 4; ++j) at[j] = __shfl(alpha, 20 * g + j);
#pragma unroll
      for (int fo = 0; fo < 8; ++fo)
#pragma unroll
        for (int j = 0; j < 4; ++j) Ot[fo][j] *= at[j];
    }

    float ps = 0.f;
#pragma unroll
    for (int f = 0; f < 4; ++f)
#pragma unroll
      for (int j = 0; j < 4; ++j) { float pp = exp2f(zv[f][j] - m_r); zv[f][j] = pp; ps += pp; }
    ps += __shfl_xor(ps, 16);
    ps += __shfl_xor(ps, 32);
    l_r = l_r * alpha + ps;

    // ---- P -> LDS (per-wave, granule-XOR) ----
    bf16* pw = (bf16*)QRS[w];
#pragma unroll
    for (int f = 0; f < 4; ++f)
#pragma unroll
      for (int j = 0; j < 4; ++j) {
        int t = 16 * f + 4 * g + j;
        pw[c * 80 + ((((t >> 3) ^ (c & 7)) << 3) | (t & 7))] = tobf(zv[f][j]);
      }

    __syncthreads();                 // barB: drains V(tt); all waves done reading Ks
    const bool more = (tt + 1 < Tend);
    if (more) stageK();              // K(tt+1) -> Ks (lands by next barA)
    if (more) {                      // rf(tt+1) global->reg (drained at next barA)
#pragma unroll
      for (int f2 = 0; f2 < 5; ++f2) {
#pragma unroll
        for (int kk = 0; kk < 4; ++kk) rf[f2][kk] = *(const bf16x8*)(rp[f2] + kk * 32);
        rp[f2] += 64 * 128;
      }
    }

    // ---- O += P V ----
    __builtin_amdgcn_s_setprio(1);
#pragma unroll
    for (int kk2 = 0; kk2 < 2; ++kk2) {
      bf16x8 pa = *(const bf16x8*)(pw + c * 80 + (((4 * kk2 + g) ^ (c & 7)) << 3));
#pragma unroll
      for (int fo = 0; fo < 8; ++fo) {
        int e = 16 * fo + c;
        bf16x8 vf = *(const bf16x8*)((const char*)Vs + e * 128 + (((4 * kk2 + g) ^ (c & 7)) << 4));
        Ot[fo] = MFMA(pa, vf, Ot[fo]);
      }
    }
    __builtin_amdgcn_s_setprio(0);
  }

  // ---- partial epilogue: normalized O-hat (f16) + (m, l) f32 ----
  if (g == 0) {
    part_m[pidx * 64 + 16 * w + c] = m_r;
    part_l[pidx * 64 + 16 * w + c] = l_r;
  }
  float linv[4];
#pragma unroll
  for (int j = 0; j < 4; ++j) linv[j] = 1.f / __shfl(l_r, 20 * g + j);
  f16* po = part_O + (size_t)pidx * 8192;
#pragma unroll
  for (int j = 0; j < 4; ++j) {
    int sl = 16 * w + 4 * g + j;
#pragma unroll
    for (int fo = 0; fo < 8; ++fo)
      po[sl * 128 + 16 * fo + c] = (f16)(Ot[fo][j] * linv[j]);
  }
}

// ---------------- combine partial halves -> att2 scatter ----------------
__global__ __launch_bounds__(256) void k_combine(
    const f16* __restrict__ part_O, const float* __restrict__ part_m,
    const float* __restrict__ part_l, bf16* __restrict__ att2)
{
  int ss = blockIdx.x;             // 0..511: strip (bh = ss>>4, qb = ss&15)
  int bh = ss >> 4, qb = ss & 15;
  int p1 = (bh << 5) | (qb << 1), p2 = p1 | 1;
  int r = threadIdx.x >> 2;        // 0..63
  int e0 = (threadIdx.x & 3) * 32;
  float m1 = part_m[p1 * 64 + r], m2 = part_m[p2 * 64 + r];
  float l1 = part_l[p1 * 64 + r], l2 = part_l[p2 * 64 + r];
  float m = fmaxf(m1, m2);
  float a1 = exp2f(m1 - m) * l1, a2 = exp2f(m2 - m) * l2;
  float inv = 1.f / (a1 + a2);
  a1 *= inv; a2 *= inv;
  int sg = qb * 64 + r;
  int ib = bh >> 3, nh = bh & 7;
  bf16* ob = att2 + (size_t)ib * 1024 * 1024
           + ((size_t)(nh * 128 + (sg >> 3))) * 1024 + ((sg & 7) << 7);
  const f16* o1 = part_O + ((size_t)p1 * 64 + r) * 128 + e0;
  const f16* o2 = part_O + ((size_t)p2 * 64 + r) * 128 + e0;
#pragma unroll
  for (int i = 0; i < 32; i += 8) {
    f16x8 v1 = *(const f16x8*)(o1 + i);
    f16x8 v2 = *(const f16x8*)(o2 + i);
    bf16x8 o;
#pragma unroll
    for (int k = 0; k < 8; ++k) o[k] = tobf(a1 * (float)v1[k] + a2 * (float)v2[k]);
    *(bf16x8*)(ob + e0 + i) = o;
  }
}

// ---------------- y = att2 @ w_mlp + x, then LayerNorm ----------------
__global__ __launch_bounds__(256, 2) void k_mlp(
    const bf16* __restrict__ att2, const bf16* __restrict__ wmlp_bt,
    const float* __restrict__ x, const float* __restrict__ lng, const float* __restrict__ lnb,
    float* __restrict__ out)
{
  __shared__ bf16 As[64 * 128];
  __shared__ bf16 Bs[128 * 128];
  const int m0 = blockIdx.x * 64;
  const int tid = threadIdx.x;
  const int w = tid >> 6, lane = tid & 63, g = lane >> 4, c = lane & 15;

  f32x4 acc[8] = {};
  for (int ks = 0; ks < 8; ++ks) {
    int k0 = ks * 128;
    __syncthreads();
#pragma unroll
    for (int it = 0; it < 4; ++it) {
      int ch = w * 256 + it * 64 + lane;
      int row = ch >> 4, cc = ch & 15;
      GLL16(att2 + (size_t)(m0 + row) * 1024 + k0 + ((cc ^ (row & 7)) * 8),
            (char*)As + (w * 256 + it * 64) * 16);
    }
#pragma unroll
    for (int it = 0; it < 8; ++it) {
      int ch = w * 512 + it * 64 + lane;
      int n = ch >> 4, cc = ch & 15;
      GLL16(wmlp_bt + (size_t)n * 1024 + k0 + ((cc ^ (n & 7)) * 8),
            (char*)Bs + (w * 512 + it * 64) * 16);
    }
    __syncthreads();
#pragma unroll
    for (int kk = 0; kk < 4; ++kk) {
      bf16x8 a = *(const bf16x8*)((const char*)As + (16 * w + c) * 256 + (((4 * kk + g) ^ (c & 7)) << 4));
#pragma unroll
      for (int fo = 0; fo < 8; ++fo) {
        bf16x8 b = *(const bf16x8*)((const char*)Bs + (16 * fo + c) * 256 + (((4 * kk + g) ^ (c & 7)) << 4));
        acc[fo] = MFMA(a, b, acc[fo]);
      }
    }
  }
#pragma unroll
  for (int j = 0; j < 4; ++j) {
    int rg = m0 + 16 * w + 4 * g + j;
    float y[8];
    float s1 = 0.f, s2 = 0.f;
#pragma unroll
    for (int fo = 0; fo < 8; ++fo) {
      float v = acc[fo][j] + x[(size_t)rg * 128 + 16 * fo + c];
      y[fo] = v; s1 += v; s2 += v * v;
    }
#pragma unroll
    for (int d = 1; d < 16; d <<= 1) { s1 += __shfl_xor(s1, d); s2 += __shfl_xor(s2, d); }
    float mu = s1 * 0.0078125f;
    float var = s2 * 0.0078125f - mu * mu;
    float rs = rsqrtf(var + 1e-5f);
#pragma unroll
    for (int fo = 0; fo < 8; ++fo) {
      int e = 16 * fo + c;
      out[(size_t)rg * 128 + e] = (y[fo] - mu) * rs * lng[e] + lnb[e];
    }
  }
}

extern "C" void kernel_launch(void* const* d_in, const int* in_sizes, int n_in,
                              void* d_out, int out_size, void* d_ws, size_t ws_size,
                              hipStream_t stream)
{
  const float* x    = (const float*)d_in[0];
  const float* mm   = (const float*)d_in[1];
  const float* u1   = (const float*)d_in[3];
  const float* u2   = (const float*)d_in[4];
  const float* wq   = (const float*)d_in[5];
  const float* wkv  = (const float*)d_in[6];
  const float* wr   = (const float*)d_in[7];
  const float* wmlp = (const float*)d_in[8];
  const float* lng  = (const float*)d_in[9];
  const float* lnb  = (const float*)d_in[10];
  float* out = (float*)d_out;

  char* p = (char*)d_ws;
  bf16* posb    = (bf16*)p;  p += (size_t)262144 * 2;
  bf16* wq_bt   = (bf16*)p;  p += (size_t)131072 * 2;
  bf16* wkv_bt  = (bf16*)p;  p += (size_t)262144 * 2;
  bf16* wr_bt   = (bf16*)p;  p += (size_t)131072 * 2;
  bf16* wmlp_bt = (bf16*)p;  p += (size_t)131072 * 2;
  bf16* xb      = (bf16*)p;  p += (size_t)524288 * 2;
  bf16* memb    = (bf16*)p;  p += (size_t)524288 * 2;
  bf16* qhk     = (bf16*)p;  p += (size_t)4 * 8 * 1024 * 128 * 2;
  bf16* qhr     = (bf16*)p;  p += (size_t)4 * 8 * 1024 * 128 * 2;
  bf16* kh      = (bf16*)p;  p += (size_t)4 * 8 * 2048 * 128 * 2;
  bf16* vh      = (bf16*)p;  p += (size_t)4 * 8 * 2048 * 128 * 2;
  bf16* vht     = (bf16*)p;  p += (size_t)4 * 8 * 2048 * 128 * 2;
  bf16* rhe     = (bf16*)p;  p += (size_t)8 * 2112 * 128 * 2;
  bf16* att2    = (bf16*)p;  p += (size_t)4 * 1024 * 1024 * 2;

  // partials aliased over buffers that are dead by the time k_flash runs:
  f16*   part_O = (f16*)vh;                 // 1024*64*128*2B = 16 MB == sizeof(vh)
  float* part_m = (float*)posb;             // 1024*64*4B = 256 KB
  float* part_l = (float*)posb + 65536;     // +256 KB == sizeof(posb)

  k_prep<<<dim3(2688), dim3(256), 0, stream>>>(x, mm, wq, wkv, wr, wmlp,
                                               posb, wq_bt, wkv_bt, wr_bt, wmlp_bt, xb, memb);
  k_proj<0><<<dim3(64, 8),   dim3(256), 0, stream>>>(xb,  (const bf16*)nullptr, wq_bt,  qhk, qhr, u1, u2);
  k_proj<1><<<dim3(128, 16), dim3(256), 0, stream>>>(xb,  memb,                 wkv_bt, kh,  vh,  nullptr, nullptr);
  k_proj<2><<<dim3(32, 8),   dim3(256), 0, stream>>>(posb,(const bf16*)nullptr, wr_bt,  rhe, (bf16*)nullptr, nullptr, nullptr);
  k_vtrans<<<dim3(32, 2, 32), dim3(256), 0, stream>>>(vh, vht);
  k_flash<<<dim3(1024), dim3(256), 0, stream>>>(qhk, qhr, kh, vht, rhe, part_O, part_m, part_l);
  k_combine<<<dim3(512), dim3(256), 0, stream>>>(part_O, part_m, part_l, att2);
  k_mlp<<<dim3(64), dim3(256), 0, stream>>>(att2, wmlp_bt, x, lng, lnb, out);
}

// Round 7
// 269.949 us; speedup vs baseline: 2.1067x; 1.1885x over previous
//
#include <hip/hip_runtime.h>
#include <hip/hip_bf16.h>
#include <stdint.h>

// Problem constants: B=4, SEG=1024, MEM=1024, TOTAL=2048, D=E=128, H=8
typedef __bf16 bf16;
typedef __attribute__((ext_vector_type(8))) __bf16 bf16x8;
typedef __attribute__((ext_vector_type(4))) __bf16 bf16x4;
typedef __attribute__((ext_vector_type(4))) float f32x4;

#define KSC 0.12764932952880681f  // log2(e)/sqrt(128)

__device__ __forceinline__ f32x4 MFMA(bf16x8 a, bf16x8 b, f32x4 c) {
  return __builtin_amdgcn_mfma_f32_16x16x32_bf16(a, b, c, 0, 0, 0);
}

__device__ __forceinline__ void GLL16(const void* g, void* l) {
  __builtin_amdgcn_global_load_lds(
      (const __attribute__((address_space(1))) void*)g,
      (__attribute__((address_space(3))) void*)l, 16, 0, 0);
}

__device__ __forceinline__ bf16 tobf(float f) { return (bf16)f; }

// ---------------- prep: pos (fast trig) + LDS-tiled weight transposes + bf16 converts ----------------
__global__ __launch_bounds__(256) void k_prep(
    const float* __restrict__ x, const float* __restrict__ mm,
    const float* __restrict__ wq, const float* __restrict__ wkv,
    const float* __restrict__ wr, const float* __restrict__ wmlp,
    bf16* __restrict__ posb, bf16* __restrict__ wq_bt, bf16* __restrict__ wkv_bt,
    bf16* __restrict__ wr_bt, bf16* __restrict__ wmlp_bt,
    bf16* __restrict__ xb, bf16* __restrict__ memb)
{
  __shared__ float T[32][33];
  const int b = blockIdx.x;
  const int tid = threadIdx.x;
  if (b < 1024) {  // posb[t][j], pos = enc[::-1] -> p = 2047 - t
    int id = b * 256 + tid;
    int t = id >> 7, j = id & 127;
    float p = (float)(2047 - t);
    float ang = p * exp2f(-(float)j * 0.20762050593046264f);  // 10000^(-j/64)
    float v = ((j & 1) == 0) ? __sinf(ang) : __cosf(ang);
    posb[id] = tobf(v);
    return;
  }
  if (b < 1664) {  // 32x32 LDS-tile transposes, f32 -> bf16
    int tb = b - 1024;
    const float* src; bf16* dst; int R, C, r0, c0;
    if (tb < 128)      { src = wq;   dst = wq_bt;   R = 128;  C = 1024; r0 = (tb >> 5) * 32;        c0 = (tb & 31) * 32; }
    else if (tb < 384) { int t2 = tb - 128; src = wkv;  dst = wkv_bt;  R = 128;  C = 2048; r0 = (t2 >> 6) * 32; c0 = (t2 & 63) * 32; }
    else if (tb < 512) { int t2 = tb - 384; src = wr;   dst = wr_bt;   R = 128;  C = 1024; r0 = (t2 >> 5) * 32; c0 = (t2 & 31) * 32; }
    else               { int t2 = tb - 512; src = wmlp; dst = wmlp_bt; R = 1024; C = 128;  r0 = (t2 >> 2) * 32; c0 = (t2 & 3) * 32; }
    int r = tid >> 3, c4 = (tid & 7) * 4;
    f32x4 v = *(const f32x4*)(src + (size_t)(r0 + r) * C + c0 + c4);
    T[r][c4] = v[0]; T[r][c4 + 1] = v[1]; T[r][c4 + 2] = v[2]; T[r][c4 + 3] = v[3];
    __syncthreads();
    bf16x4 o;
#pragma unroll
    for (int k = 0; k < 4; ++k) o[k] = tobf(T[c4 + k][r]);
    *(bf16x4*)(dst + (size_t)(c0 + r) * R + r0 + c4) = o;
    return;
  }
  {  // vectorized converts
    int cb = b - 1664;
    if (cb < 512) {
      int i = cb * 256 + tid;
      f32x4 v = *(const f32x4*)(x + (size_t)i * 4);
      bf16x4 o; o[0]=tobf(v[0]); o[1]=tobf(v[1]); o[2]=tobf(v[2]); o[3]=tobf(v[3]);
      *(bf16x4*)(xb + (size_t)i * 4) = o;
    } else {
      int i = (cb - 512) * 256 + tid;
      f32x4 v = *(const f32x4*)(mm + (size_t)i * 4);
      bf16x4 o; o[0]=tobf(v[0]); o[1]=tobf(v[1]); o[2]=tobf(v[2]); o[3]=tobf(v[3]);
      *(bf16x4*)(memb + (size_t)i * 4) = o;
    }
  }
}

// ---------------- projection GEMM: C[64x128 tile] = A[64x128] * W[128xN], scatter epilogue ----------------
// MODE 0: Q-proj -> out0 = (q+u1)*KSC, out1 = (q+u2)*KSC
// MODE 1: KV-proj -> out0 = k, out1 = v
// MODE 2: R-proj -> out0 = r (2112 rows: row t mirrored at 2048+t for t<64)
template <int MODE>
__global__ __launch_bounds__(256, 2) void k_proj(
    const bf16* __restrict__ asrc, const bf16* __restrict__ asrc2,
    const bf16* __restrict__ wbt, bf16* __restrict__ out0, bf16* __restrict__ out1,
    const float* __restrict__ u1, const float* __restrict__ u2)
{
  __shared__ bf16 As[64 * 128];
  __shared__ bf16 Bs[128 * 128];
  const int m0 = blockIdx.x * 64;
  const int n0 = blockIdx.y * 128;
  const int tid = threadIdx.x;
  const int w = tid >> 6, lane = tid & 63, g = lane >> 4, c = lane & 15;

#pragma unroll
  for (int it = 0; it < 4; ++it) {
    int ch = w * 256 + it * 64 + lane;
    int row = ch >> 4, cc = ch & 15;
    int scc = cc ^ (row & 7);
    const bf16* src;
    if (MODE == 1) {
      int rg = m0 + row;
      int bb = rg >> 11, t = rg & 2047;
      src = (t < 1024) ? (asrc2 + (size_t)(bb * 1024 + t) * 128)
                       : (asrc + (size_t)(bb * 1024 + (t - 1024)) * 128);
    } else {
      src = asrc + (size_t)(m0 + row) * 128;
    }
    GLL16(src + scc * 8, (char*)As + (w * 256 + it * 64) * 16);
  }
#pragma unroll
  for (int it = 0; it < 8; ++it) {
    int ch = w * 512 + it * 64 + lane;
    int n = ch >> 4, cc = ch & 15;
    int scc = cc ^ (n & 7);
    GLL16(wbt + (size_t)(n0 + n) * 128 + scc * 8, (char*)Bs + (w * 512 + it * 64) * 16);
  }
  __syncthreads();

  f32x4 acc[8] = {};
#pragma unroll
  for (int kk = 0; kk < 4; ++kk) {
    bf16x8 a = *(const bf16x8*)((const char*)As + (16 * w + c) * 256 + (((4 * kk + g) ^ (c & 7)) << 4));
#pragma unroll
    for (int fo = 0; fo < 8; ++fo) {
      bf16x8 b = *(const bf16x8*)((const char*)Bs + (16 * fo + c) * 256 + (((4 * kk + g) ^ (c & 7)) << 4));
      acc[fo] = MFMA(a, b, acc[fo]);
    }
  }

#pragma unroll
  for (int fo = 0; fo < 8; ++fo) {
#pragma unroll
    for (int j = 0; j < 4; ++j) {
      int rg = m0 + 16 * w + 4 * g + j;
      int cg = n0 + 16 * fo + c;
      float av = acc[fo][j];
      if (MODE == 0) {
        int b = rg >> 10, s2 = rg & 1023;
        int nn = s2 >> 7;
        int s = ((s2 & 127) << 3) | (cg >> 7);
        int e = cg & 127;
        size_t idx = ((size_t)((b * 8 + nn) * 1024 + s)) * 128 + e;
        out0[idx] = tobf((av + u1[nn * 128 + e]) * KSC);
        out1[idx] = tobf((av + u2[nn * 128 + e]) * KSC);
      } else if (MODE == 1) {
        int bb = rg >> 11, t = rg & 2047;
        int nn = (t >> 7) & 7;
        int hlf = (t >> 10) & 1;
        int t2 = ((t & 127) << 4) | (cg >> 7);
        int e = cg & 127;
        bf16 v = tobf(av);
        if (bb < 2)
          out0[((size_t)(((2 * bb + hlf) * 8 + nn) * 2048 + t2)) * 128 + e] = v;
        else
          out1[((size_t)(((2 * (bb - 2) + hlf) * 8 + nn) * 2048 + t2)) * 128 + e] = v;
      } else {
        int nn = rg >> 8;
        int t = ((rg & 255) << 3) | (cg >> 7);
        int e = cg & 127;
        bf16 v = tobf(av);
        out0[((size_t)(nn * 2112 + t)) * 128 + e] = v;
        if (t < 64) out0[((size_t)(nn * 2112 + 2048 + t)) * 128 + e] = v;  // wrap extension
      }
    }
  }
}

// ---------------- V transpose: vh[bh][t][e] -> vht[bh][e][t] ----------------
__global__ __launch_bounds__(256) void k_vtrans(const bf16* __restrict__ vh, bf16* __restrict__ vht)
{
  __shared__ bf16 T[64][72];
  int bt = blockIdx.x * 64, be = blockIdx.y * 64, bh = blockIdx.z;
  const bf16* src = vh + (size_t)bh * 2048 * 128;
  bf16* dst = vht + (size_t)bh * 128 * 2048;
#pragma unroll
  for (int i2 = 0; i2 < 2; ++i2) {
    int ch = i2 * 256 + threadIdx.x;
    int tt = ch >> 3, cc = ch & 7;
    bf16x8 v = *(const bf16x8*)(src + (size_t)(bt + tt) * 128 + be + cc * 8);
    *(bf16x8*)&T[tt][cc * 8] = v;
  }
  __syncthreads();
#pragma unroll
  for (int i2 = 0; i2 < 2; ++i2) {
    int ch = i2 * 256 + threadIdx.x;
    int ee = ch >> 3, c2 = ch & 7;
    bf16x8 o;
#pragma unroll
    for (int m = 0; m < 8; ++m) o[m] = T[c2 * 8 + m][ee];
    *(bf16x8*)(dst + (size_t)(be + ee) * 2048 + bt + c2 * 8) = o;
  }
}

// ---------------- flash attention, swapped-operand layout, XCD-locality mapping ----------------
// R4-proven core: K/V double-buffer, ONE barrier/tile (full-tile prefetch distance),
// R register pipeline consumed one tile after issue, direct att2 epilogue.
// Block mapping: xcd = x&7 (HW round-robin) -> bh = 8*(k2&3) + xcd, so ALL blocks on an
// XCD share nh = bh&7 = xcd: one 540 KB R panel per XCD, L2-resident; 4 bh K/V streams
// advance in lockstep from t=0. qb paired (i, 15-i) across CU slots for even finish.
__global__ __launch_bounds__(256, 2) void k_flash(
    const bf16* __restrict__ qhk, const bf16* __restrict__ qhr,
    const bf16* __restrict__ kh, const bf16* __restrict__ vht,
    const bf16* __restrict__ rhe, bf16* __restrict__ att2)
{
  __shared__ bf16 Ks[2][64 * 128];   // [t][e], chunk-XOR swizzled
  __shared__ bf16 Vs[2][64 * 128];   // [e][t], chunk-XOR swizzled
  __shared__ char QRS[4][2688];      // per-wave: qr [16 x stride 82]; P aliased [16 x stride 80]

  const int x = blockIdx.x;
  const int xcd = x & 7;
  const int k2 = x >> 3;                       // 0..63
  const int bh = 8 * (k2 & 3) + xcd;           // nh = xcd for every block on this XCD
  const int qb = (k2 < 32) ? (k2 >> 2) : (23 - (k2 >> 2));  // pair (i,15-i): 49 tiles/slot-pair
  const int ib = bh >> 3, nh = bh & 7;
  const int s0 = qb * 64;
  const int tid = threadIdx.x;
  const int w = tid >> 6, lane = tid & 63, g = lane >> 4, c = lane & 15;

  const bf16* qkb  = qhk + (size_t)bh * 1024 * 128;
  const bf16* qrb  = qhr + (size_t)bh * 1024 * 128;
  const bf16* kbase = kh + (size_t)bh * 2048 * 128;
  const bf16* vbase = vht + (size_t)bh * 128 * 2048;
  const bf16* rbase = rhe + (size_t)nh * 2112 * 128;

  const int nt = qb + 17;  // keys needed: t <= s0+63+1024

  // ---- strength-reduced stage pointers ----
  const bf16 *kp0, *kp1, *vp0, *vp1, *vp2, *vp3;
  {
    int ch0 = w * 256 + lane;
    int ch1 = ch0 + 64;
    int r0 = ch0 >> 4, cc0 = ch0 & 15;
    int r1 = ch1 >> 4, cc1 = ch1 & 15;
    kp0 = kbase + (size_t)r0 * 128 + (cc0 ^ (r0 & 7)) * 8;
    kp1 = kbase + (size_t)r1 * 128 + (cc1 ^ (r1 & 7)) * 8;
    int e0 = ch0 >> 3, t0c = ch0 & 7;
    int e1 = ch1 >> 3, t1c = ch1 & 7;
    int e2 = e0 + 16, e3 = e1 + 16;
    vp0 = vbase + (size_t)e0 * 2048 + (t0c ^ (e0 & 7)) * 8;
    vp1 = vbase + (size_t)e1 * 2048 + (t1c ^ (e1 & 7)) * 8;
    vp2 = vbase + (size_t)e2 * 2048 + (t0c ^ (e2 & 7)) * 8;
    vp3 = vbase + (size_t)e3 * 2048 + (t1c ^ (e3 & 7)) * 8;
  }
  const int dof = (w * 256 + lane) * 16;

  auto stage = [&](int pb) {
    char* Kd = (char*)Ks[pb];
    char* Vd = (char*)Vs[pb];
    GLL16(kp0, Kd + dof);
    GLL16(kp1, Kd + dof + 1024);
    GLL16(kp0 + 1024, Kd + dof + 2048);
    GLL16(kp1 + 1024, Kd + dof + 3072);
    GLL16(vp0, Vd + dof);
    GLL16(vp1, Vd + dof + 1024);
    GLL16(vp2, Vd + dof + 2048);
    GLL16(vp3, Vd + dof + 3072);
    kp0 += 8192; kp1 += 8192;
    vp0 += 64; vp1 += 64; vp2 += 64; vp3 += 64;
  };

  // ---- Q fragments (u-terms pre-folded, prescaled) ----
  bf16x8 qfK[4], qfR[4];
  {
    int srow = s0 + 16 * w + c;
#pragma unroll
    for (int kk = 0; kk < 4; ++kk) {
      qfK[kk] = *(const bf16x8*)(qkb + (size_t)srow * 128 + kk * 32 + g * 8);
      qfR[kk] = *(const bf16x8*)(qrb + (size_t)srow * 128 + kk * 32 + g * 8);
    }
  }

  // ---- R register pipeline (mod-free 2112-row rhe) ----
  bf16x8 rf[5][4];
  const bf16* rp[5];
  {
    const int L0 = 1008 - s0 - 16 * w + c;
#pragma unroll
    for (int f2 = 0; f2 < 5; ++f2) {
      rp[f2] = rbase + (size_t)(L0 + 16 * f2) * 128 + g * 8;
#pragma unroll
      for (int kk = 0; kk < 4; ++kk) rf[f2][kk] = *(const bf16x8*)(rp[f2] + kk * 32);
      rp[f2] += 64 * 128;
    }
  }

  f32x4 Ot[8] = {};
  float m_r = -1e30f, l_r = 0.f;   // per-lane: row s = c of group w

  stage(0);

  for (int tt = 0; tt < nt; ++tt) {
    __syncthreads();               // drains stage(tt) + rf(tt); protects buf (tt+1)&1 WAR
    const bool notlast = (tt + 1 < nt);
    if (notlast) stage((tt + 1) & 1);

    const bf16* Kc = Ks[tt & 1];
    const bf16* Vc = Vs[tt & 1];

    // ---- S^T = K Q^T : sacc[f][j] = S[s=c][t = 16f+4g+j] ----
    f32x4 sacc[4] = {};
    __builtin_amdgcn_s_setprio(1);
#pragma unroll
    for (int kk = 0; kk < 4; ++kk) {
#pragma unroll
      for (int f = 0; f < 4; ++f) {
        bf16x8 kf = *(const bf16x8*)((const char*)Kc + (16 * f + c) * 256 + (((4 * kk + g) ^ (c & 7)) << 4));
        sacc[f] = MFMA(kf, qfK[kk], sacc[f]);
      }
    }
    // ---- QR^T: bacc[f2][j] = QR[s=c][W = 16f2+4g+j] ----
    f32x4 bacc[5] = {};
#pragma unroll
    for (int f2 = 0; f2 < 5; ++f2)
#pragma unroll
      for (int kk = 0; kk < 4; ++kk)
        bacc[f2] = MFMA(rf[f2][kk], qfR[kk], bacc[f2]);
    __builtin_amdgcn_s_setprio(0);

    // ---- qr -> per-wave LDS [s=c][W], stride 82 ----
    bf16* qrw = (bf16*)QRS[w];
#pragma unroll
    for (int f2 = 0; f2 < 5; ++f2)
#pragma unroll
      for (int j = 0; j < 4; ++j)
        qrw[c * 82 + 16 * f2 + 4 * g + j] = tobf(bacc[f2][j]);

    // ---- prefetch R fragments for tile tt+1 (consumed next tile) ----
    if (notlast) {
#pragma unroll
      for (int f2 = 0; f2 < 5; ++f2) {
#pragma unroll
        for (int kk = 0; kk < 4; ++kk) rf[f2][kk] = *(const bf16x8*)(rp[f2] + kk * 32);
        rp[f2] += 64 * 128;
      }
    }

    // ---- compose scores: z = S + bias(W = tl - c + 15); mask last tile ----
    float zv[4][4];
#pragma unroll
    for (int f = 0; f < 4; ++f)
#pragma unroll
      for (int j = 0; j < 4; ++j) {
        int tl = 16 * f + 4 * g + j;
        float z = sacc[f][j] + (float)qrw[c * 82 + (tl - c + 15)];
        if (!notlast && (tl > 16 * w + c)) z = -1e30f;
        zv[f][j] = z;
      }

    // ---- online softmax: lane owns row c; in-lane reduce + 2 shuffles; defer-max ----
    float pm = fmaxf(fmaxf(fmaxf(zv[0][0], zv[0][1]), fmaxf(zv[0][2], zv[0][3])),
                     fmaxf(fmaxf(zv[1][0], zv[1][1]), fmaxf(zv[1][2], zv[1][3])));
    float pm2 = fmaxf(fmaxf(fmaxf(zv[2][0], zv[2][1]), fmaxf(zv[2][2], zv[2][3])),
                      fmaxf(fmaxf(zv[3][0], zv[3][1]), fmaxf(zv[3][2], zv[3][3])));
    pm = fmaxf(pm, pm2);
    pm = fmaxf(pm, __shfl_xor(pm, 16));
    pm = fmaxf(pm, __shfl_xor(pm, 32));

    float alpha = 1.f;
    if (!__all(pm <= m_r + 8.0f)) {
      float mn = fmaxf(m_r, pm);
      alpha = exp2f(m_r - mn);
      m_r = mn;
      float at[4];
#pragma unroll
      for (int j = 0; j < 4; ++j) at[j] = __shfl(alpha, 20 * g + j);
#pragma unroll
      for (int fo = 0; fo < 8; ++fo)
#pragma unroll
        for (int j = 0; j < 4; ++j) Ot[fo][j] *= at[j];
    }

    float ps = 0.f;
#pragma unroll
    for (int f = 0; f < 4; ++f)
#pragma unroll
      for (int j = 0; j < 4; ++j) { float pp = exp2f(zv[f][j] - m_r); zv[f][j] = pp; ps += pp; }
    ps += __shfl_xor(ps, 16);
    ps += __shfl_xor(ps, 32);
    l_r = l_r * alpha + ps;

    // ---- P -> LDS (per-wave, granule-XOR) ----
    bf16* pw = (bf16*)QRS[w];
#pragma unroll
    for (int f = 0; f < 4; ++f)
#pragma unroll
      for (int j = 0; j < 4; ++j) {
        int t = 16 * f + 4 * g + j;
        pw[c * 80 + ((((t >> 3) ^ (c & 7)) << 3) | (t & 7))] = tobf(zv[f][j]);
      }

    // ---- O += P V ----
    __builtin_amdgcn_s_setprio(1);
#pragma unroll
    for (int kk2 = 0; kk2 < 2; ++kk2) {
      bf16x8 pa = *(const bf16x8*)(pw + c * 80 + (((4 * kk2 + g) ^ (c & 7)) << 3));
#pragma unroll
      for (int fo = 0; fo < 8; ++fo) {
        int e = 16 * fo + c;
        bf16x8 vf = *(const bf16x8*)((const char*)Vc + e * 128 + (((4 * kk2 + g) ^ (c & 7)) << 4));
        Ot[fo] = MFMA(pa, vf, Ot[fo]);
      }
    }
    __builtin_amdgcn_s_setprio(0);
  }

  // ---- epilogue: transpose l to row space, divide, scatter into att2 ----
  float linv[4];
#pragma unroll
  for (int j = 0; j < 4; ++j) linv[j] = 1.f / __shfl(l_r, 20 * g + j);
  bf16* ob = att2 + (size_t)ib * 1024 * 1024;
#pragma unroll
  for (int j = 0; j < 4; ++j) {
    int sg = s0 + 16 * w + 4 * g + j;
    size_t rowb = (size_t)(nh * 128 + (sg >> 3)) * 1024 + ((sg & 7) << 7);
#pragma unroll
    for (int fo = 0; fo < 8; ++fo)
      ob[rowb + 16 * fo + c] = tobf(Ot[fo][j] * linv[j]);
  }
}

// ---------------- y = att2 @ w_mlp + x, then LayerNorm ----------------
__global__ __launch_bounds__(256, 2) void k_mlp(
    const bf16* __restrict__ att2, const bf16* __restrict__ wmlp_bt,
    const float* __restrict__ x, const float* __restrict__ lng, const float* __restrict__ lnb,
    float* __restrict__ out)
{
  __shared__ bf16 As[64 * 128];
  __shared__ bf16 Bs[128 * 128];
  const int m0 = blockIdx.x * 64;
  const int tid = threadIdx.x;
  const int w = tid >> 6, lane = tid & 63, g = lane >> 4, c = lane & 15;

  f32x4 acc[8] = {};
  for (int ks = 0; ks < 8; ++ks) {
    int k0 = ks * 128;
    __syncthreads();
#pragma unroll
    for (int it = 0; it < 4; ++it) {
      int ch = w * 256 + it * 64 + lane;
      int row = ch >> 4, cc = ch & 15;
      GLL16(att2 + (size_t)(m0 + row) * 1024 + k0 + ((cc ^ (row & 7)) * 8),
            (char*)As + (w * 256 + it * 64) * 16);
    }
#pragma unroll
    for (int it = 0; it < 8; ++it) {
      int ch = w * 512 + it * 64 + lane;
      int n = ch >> 4, cc = ch & 15;
      GLL16(wmlp_bt + (size_t)n * 1024 + k0 + ((cc ^ (n & 7)) * 8),
            (char*)Bs + (w * 512 + it * 64) * 16);
    }
    __syncthreads();
#pragma unroll
    for (int kk = 0; kk < 4; ++kk) {
      bf16x8 a = *(const bf16x8*)((const char*)As + (16 * w + c) * 256 + (((4 * kk + g) ^ (c & 7)) << 4));
#pragma unroll
      for (int fo = 0; fo < 8; ++fo) {
        bf16x8 b = *(const bf16x8*)((const char*)Bs + (16 * fo + c) * 256 + (((4 * kk + g) ^ (c & 7)) << 4));
        acc[fo] = MFMA(a, b, acc[fo]);
      }
    }
  }
#pragma unroll
  for (int j = 0; j < 4; ++j) {
    int rg = m0 + 16 * w + 4 * g + j;
    float y[8];
    float s1 = 0.f, s2 = 0.f;
#pragma unroll
    for (int fo = 0; fo < 8; ++fo) {
      float v = acc[fo][j] + x[(size_t)rg * 128 + 16 * fo + c];
      y[fo] = v; s1 += v; s2 += v * v;
    }
#pragma unroll
    for (int d = 1; d < 16; d <<= 1) { s1 += __shfl_xor(s1, d); s2 += __shfl_xor(s2, d); }
    float mu = s1 * 0.0078125f;
    float var = s2 * 0.0078125f - mu * mu;
    float rs = rsqrtf(var + 1e-5f);
#pragma unroll
    for (int fo = 0; fo < 8; ++fo) {
      int e = 16 * fo + c;
      out[(size_t)rg * 128 + e] = (y[fo] - mu) * rs * lng[e] + lnb[e];
    }
  }
}

extern "C" void kernel_launch(void* const* d_in, const int* in_sizes, int n_in,
                              void* d_out, int out_size, void* d_ws, size_t ws_size,
                              hipStream_t stream)
{
  const float* x    = (const float*)d_in[0];
  const float* mm   = (const float*)d_in[1];
  const float* u1   = (const float*)d_in[3];
  const float* u2   = (const float*)d_in[4];
  const float* wq   = (const float*)d_in[5];
  const float* wkv  = (const float*)d_in[6];
  const float* wr   = (const float*)d_in[7];
  const float* wmlp = (const float*)d_in[8];
  const float* lng  = (const float*)d_in[9];
  const float* lnb  = (const float*)d_in[10];
  float* out = (float*)d_out;

  char* p = (char*)d_ws;
  bf16* posb    = (bf16*)p;  p += (size_t)262144 * 2;
  bf16* wq_bt   = (bf16*)p;  p += (size_t)131072 * 2;
  bf16* wkv_bt  = (bf16*)p;  p += (size_t)262144 * 2;
  bf16* wr_bt   = (bf16*)p;  p += (size_t)131072 * 2;
  bf16* wmlp_bt = (bf16*)p;  p += (size_t)131072 * 2;
  bf16* xb      = (bf16*)p;  p += (size_t)524288 * 2;
  bf16* memb    = (bf16*)p;  p += (size_t)524288 * 2;
  bf16* qhk     = (bf16*)p;  p += (size_t)4 * 8 * 1024 * 128 * 2;
  bf16* qhr     = (bf16*)p;  p += (size_t)4 * 8 * 1024 * 128 * 2;
  bf16* kh      = (bf16*)p;  p += (size_t)4 * 8 * 2048 * 128 * 2;
  bf16* vh      = (bf16*)p;  p += (size_t)4 * 8 * 2048 * 128 * 2;
  bf16* vht     = (bf16*)p;  p += (size_t)4 * 8 * 2048 * 128 * 2;
  bf16* rhe     = (bf16*)p;  p += (size_t)8 * 2112 * 128 * 2;
  bf16* att2    = (bf16*)p;  p += (size_t)4 * 1024 * 1024 * 2;

  k_prep<<<dim3(2688), dim3(256), 0, stream>>>(x, mm, wq, wkv, wr, wmlp,
                                               posb, wq_bt, wkv_bt, wr_bt, wmlp_bt, xb, memb);
  k_proj<0><<<dim3(64, 8),   dim3(256), 0, stream>>>(xb,  (const bf16*)nullptr, wq_bt,  qhk, qhr, u1, u2);
  k_proj<1><<<dim3(128, 16), dim3(256), 0, stream>>>(xb,  memb,                 wkv_bt, kh,  vh,  nullptr, nullptr);
  k_proj<2><<<dim3(32, 8),   dim3(256), 0, stream>>>(posb,(const bf16*)nullptr, wr_bt,  rhe, (bf16*)nullptr, nullptr, nullptr);
  k_vtrans<<<dim3(32, 2, 32), dim3(256), 0, stream>>>(vh, vht);
  k_flash<<<dim3(512), dim3(256), 0, stream>>>(qhk, qhr, kh, vht, rhe, att2);
  k_mlp<<<dim3(64), dim3(256), 0, stream>>>(att2, wmlp_bt, x, lng, lnb, out);
}